// Round 1
// baseline (489.171 us; speedup 1.0000x reference)
//
#include <hip/hip_runtime.h>
#include <math.h>

#define B_ 8
#define T_ 2048
#define D_ 1024
#define HS_ 64
#define M_TOTAL (B_*T_)

// ---------------------------------------------------------------------------
// Kernel 1: fused QKV projection.  C[m][n], n in [0,192) = q|k|v, m over B*T.
// M-tile 64, N = 192, K-chunk 16.  256 threads, micro-tile 4 rows x 12 cols.
// ---------------------------------------------------------------------------
__global__ __launch_bounds__(256) void qkv_kernel(
    const float* __restrict__ x,  const float* __restrict__ Wq,
    const float* __restrict__ Wk, const float* __restrict__ Wv,
    float* __restrict__ qo, float* __restrict__ ko, float* __restrict__ vo)
{
    __shared__ float As[16][68];   // [k][m], pad 68 keeps float4 reads aligned
    __shared__ float Bs[16][192];  // [k][n]

    const int t  = threadIdx.x;
    const int m0 = blockIdx.x * 64;
    const int tm = t & 15;   // row group: rows tm*4 .. tm*4+3
    const int tn = t >> 4;   // col group: cols tn*12 .. tn*12+11

    const int lr  = t >> 2;         // A-load: row 0..63
    const int lk4 = (t & 3) * 4;    // A-load: k offset 0,4,8,12
    const int bk  = t >> 4;         // B-load: k row 0..15
    const int bh4 = (t & 15) * 4;   // B-load: h offset 0..60

    float acc[4][12];
#pragma unroll
    for (int i = 0; i < 4; ++i)
#pragma unroll
        for (int j = 0; j < 12; ++j) acc[i][j] = 0.f;

    for (int kc = 0; kc < D_; kc += 16) {
        // stage A (x tile, transposed) -----------------------------------
        float4 av = *(const float4*)&x[(size_t)(m0 + lr) * D_ + kc + lk4];
        As[lk4 + 0][lr] = av.x;
        As[lk4 + 1][lr] = av.y;
        As[lk4 + 2][lr] = av.z;
        As[lk4 + 3][lr] = av.w;
        // stage B (Wq|Wk|Wv chunk) ---------------------------------------
        *(float4*)&Bs[bk][bh4]       = *(const float4*)&Wq[(size_t)(kc + bk) * HS_ + bh4];
        *(float4*)&Bs[bk][64  + bh4] = *(const float4*)&Wk[(size_t)(kc + bk) * HS_ + bh4];
        *(float4*)&Bs[bk][128 + bh4] = *(const float4*)&Wv[(size_t)(kc + bk) * HS_ + bh4];
        __syncthreads();

#pragma unroll
        for (int kk = 0; kk < 16; ++kk) {
            float4 a  = *(const float4*)&As[kk][tm * 4];
            float4 b0 = *(const float4*)&Bs[kk][tn * 12];
            float4 b1 = *(const float4*)&Bs[kk][tn * 12 + 4];
            float4 b2 = *(const float4*)&Bs[kk][tn * 12 + 8];
            float aa[4]  = {a.x, a.y, a.z, a.w};
            float bb[12] = {b0.x, b0.y, b0.z, b0.w,
                            b1.x, b1.y, b1.z, b1.w,
                            b2.x, b2.y, b2.z, b2.w};
#pragma unroll
            for (int i = 0; i < 4; ++i)
#pragma unroll
                for (int j = 0; j < 12; ++j)
                    acc[i][j] += aa[i] * bb[j];
        }
        __syncthreads();
    }

    // write out ----------------------------------------------------------
#pragma unroll
    for (int i = 0; i < 4; ++i) {
        const size_t row = (size_t)(m0 + tm * 4 + i);
#pragma unroll
        for (int j = 0; j < 12; ++j) {
            const int n = tn * 12 + j;
            const float vvv = acc[i][j];
            if (n < 64)       qo[row * HS_ + n]        = vvv;
            else if (n < 128) ko[row * HS_ + (n - 64)] = vvv;
            else              vo[row * HS_ + (n - 128)] = vvv;
        }
    }
}

// ---------------------------------------------------------------------------
// Kernel 2: causal flash attention, fp32.
// One block per (batch, 64-query tile).  K/V tiles of 64 in LDS.
// ---------------------------------------------------------------------------
__global__ __launch_bounds__(256) void attn_kernel(
    const float* __restrict__ q, const float* __restrict__ k,
    const float* __restrict__ v, float* __restrict__ out)
{
    __shared__ float QsT[64][68];   // [h][q-row]
    __shared__ float KsT[64][68];   // [h][k-row]
    __shared__ float Vs [64][68];   // [k-row][h]
    __shared__ float PsT[64][68];   // [k-row][q-row]  (scores, then probs)
    __shared__ float alphas_s[64];
    __shared__ float linv_s[64];

    const int t  = threadIdx.x;
    const int qi = blockIdx.x;          // 0..31 query tile
    const int b  = blockIdx.y;          // 0..7 batch
    const int q0 = qi * 64;
    const size_t base = (size_t)b * T_ * HS_;

    const int lr = t >> 2;              // loader row 0..63
    const int lh = (t & 3) * 16;        // loader h base (4 float4s each)

    // load Q tile transposed ---------------------------------------------
#pragma unroll
    for (int ii = 0; ii < 4; ++ii) {
        float4 qv = *(const float4*)&q[base + (size_t)(q0 + lr) * HS_ + lh + ii * 4];
        QsT[lh + ii * 4 + 0][lr] = qv.x;
        QsT[lh + ii * 4 + 1][lr] = qv.y;
        QsT[lh + ii * 4 + 2][lr] = qv.z;
        QsT[lh + ii * 4 + 3][lr] = qv.w;
    }

    const int tm = t & 15;              // q-row group
    const int tn = t >> 4;              // col group (key cols in S, h cols in O)

    float o[4][4];
#pragma unroll
    for (int i = 0; i < 4; ++i)
#pragma unroll
        for (int j = 0; j < 4; ++j) o[i][j] = 0.f;
    float m_prev = -1e30f, l_run = 0.f;

    for (int kt = 0; kt <= qi; ++kt) {
        const int k0 = kt * 64;
        // stage K (transposed) and V (direct) ----------------------------
#pragma unroll
        for (int ii = 0; ii < 4; ++ii) {
            float4 kv = *(const float4*)&k[base + (size_t)(k0 + lr) * HS_ + lh + ii * 4];
            KsT[lh + ii * 4 + 0][lr] = kv.x;
            KsT[lh + ii * 4 + 1][lr] = kv.y;
            KsT[lh + ii * 4 + 2][lr] = kv.z;
            KsT[lh + ii * 4 + 3][lr] = kv.w;
            float4 vv = *(const float4*)&v[base + (size_t)(k0 + lr) * HS_ + lh + ii * 4];
            *(float4*)&Vs[lr][lh + ii * 4] = vv;
        }
        __syncthreads();

        // S = Q.K^T ------------------------------------------------------
        float s[4][4];
#pragma unroll
        for (int i = 0; i < 4; ++i)
#pragma unroll
            for (int j = 0; j < 4; ++j) s[i][j] = 0.f;
#pragma unroll 8
        for (int h = 0; h < 64; ++h) {
            float4 a  = *(const float4*)&QsT[h][tm * 4];
            float4 bb = *(const float4*)&KsT[h][tn * 4];
            float aa[4] = {a.x, a.y, a.z, a.w};
            float bv[4] = {bb.x, bb.y, bb.z, bb.w};
#pragma unroll
            for (int i = 0; i < 4; ++i)
#pragma unroll
                for (int j = 0; j < 4; ++j)
                    s[i][j] += aa[i] * bv[j];
        }
        // scale + causal mask + write scores transposed ------------------
#pragma unroll
        for (int i = 0; i < 4; ++i)
#pragma unroll
            for (int j = 0; j < 4; ++j) {
                float val = s[i][j] * 0.125f;   // HS^-0.5 = 1/8
                if (k0 + tn * 4 + j > q0 + tm * 4 + i) val = -1e30f;
                PsT[tn * 4 + j][tm * 4 + i] = val;
            }
        __syncthreads();

        // online softmax (row owners: t < 64) ----------------------------
        if (t < 64) {
            float tmax = -1e30f;
#pragma unroll 8
            for (int j = 0; j < 64; ++j) tmax = fmaxf(tmax, PsT[j][t]);
            const float m_new = fmaxf(m_prev, tmax);
            const float alpha = __expf(m_prev - m_new);
            float sum = 0.f;
#pragma unroll 8
            for (int j = 0; j < 64; ++j) {
                float p = __expf(PsT[j][t] - m_new);
                PsT[j][t] = p;
                sum += p;
            }
            l_run = l_run * alpha + sum;
            m_prev = m_new;
            alphas_s[t] = alpha;
        }
        __syncthreads();

        // O = O*alpha + P.V ----------------------------------------------
        float al[4];
#pragma unroll
        for (int i = 0; i < 4; ++i) al[i] = alphas_s[tm * 4 + i];
#pragma unroll
        for (int i = 0; i < 4; ++i)
#pragma unroll
            for (int j = 0; j < 4; ++j) o[i][j] *= al[i];
#pragma unroll 8
        for (int kk2 = 0; kk2 < 64; ++kk2) {
            float4 a  = *(const float4*)&PsT[kk2][tm * 4];
            float4 bb = *(const float4*)&Vs[kk2][tn * 4];
            float aa[4] = {a.x, a.y, a.z, a.w};
            float bv[4] = {bb.x, bb.y, bb.z, bb.w};
#pragma unroll
            for (int i = 0; i < 4; ++i)
#pragma unroll
                for (int j = 0; j < 4; ++j)
                    o[i][j] += aa[i] * bv[j];
        }
        __syncthreads();
    }

    if (t < 64) linv_s[t] = 1.0f / l_run;
    __syncthreads();

#pragma unroll
    for (int i = 0; i < 4; ++i) {
        const int row = q0 + tm * 4 + i;
        const float li = linv_s[tm * 4 + i];
        float4 res;
        res.x = o[i][0] * li;
        res.y = o[i][1] * li;
        res.z = o[i][2] * li;
        res.w = o[i][3] * li;
        *(float4*)&out[base + (size_t)row * HS_ + tn * 4] = res;
    }
}

// ---------------------------------------------------------------------------
extern "C" void kernel_launch(void* const* d_in, const int* in_sizes, int n_in,
                              void* d_out, int out_size, void* d_ws, size_t ws_size,
                              hipStream_t stream)
{
    const float* x  = (const float*)d_in[0];
    const float* Wq = (const float*)d_in[1];
    const float* Wk = (const float*)d_in[2];
    const float* Wv = (const float*)d_in[3];
    float* out = (float*)d_out;

    float* ws = (float*)d_ws;
    const size_t qkv_elems = (size_t)M_TOTAL * HS_;   // 1,048,576 floats each
    float* qp = ws;
    float* kp = ws + qkv_elems;
    float* vp = ws + 2 * qkv_elems;

    // Stage 1: QKV projection
    qkv_kernel<<<M_TOTAL / 64, 256, 0, stream>>>(x, Wq, Wk, Wv, qp, kp, vp);
    // Stage 2: causal flash attention
    attn_kernel<<<dim3(T_ / 64, B_), 256, 0, stream>>>(qp, kp, vp, out);
}

// Round 2
// 193.747 us; speedup vs baseline: 2.5248x; 2.5248x over previous
//
#include <hip/hip_runtime.h>
#include <math.h>

#define B_ 8
#define T_ 2048
#define D_ 1024
#define HS_ 64

typedef _Float16 f16x8 __attribute__((ext_vector_type(8)));
typedef float f32x4 __attribute__((ext_vector_type(4)));

// ---------------------------------------------------------------------------
// ws layout (f16 elements):
//   qf : [B*T][64]        offset 0         (1,048,576 elems)
//   kf : [B*T][64]        offset 1,048,576
//   vT : [B][64][T]       offset 2,097,152 (1,048,576)
//   Wt : [192][1024]      offset 3,145,728 (196,608)   rows: Wq^T|Wk^T|Wv^T
// total ~6.7 MB
// ---------------------------------------------------------------------------

// Stage 0: transpose Wq|Wk|Wv (fp32 [1024][64]) -> Wt f16 [192][1024]
__global__ __launch_bounds__(256) void wt_kernel(
    const float* __restrict__ Wq, const float* __restrict__ Wk,
    const float* __restrict__ Wv, _Float16* __restrict__ Wt)
{
    __shared__ _Float16 Tt[64][72];
    const float* W = (blockIdx.y == 0) ? Wq : (blockIdx.y == 1) ? Wk : Wv;
    const int t  = threadIdx.x;
    const int k0 = blockIdx.x * 64;
    {
        const int r = t >> 2, c0 = (t & 3) * 16;
#pragma unroll
        for (int i = 0; i < 4; ++i) {
            float4 w = *(const float4*)&W[(size_t)(k0 + r) * HS_ + c0 + i * 4];
            Tt[c0 + i * 4 + 0][r] = (_Float16)w.x;
            Tt[c0 + i * 4 + 1][r] = (_Float16)w.y;
            Tt[c0 + i * 4 + 2][r] = (_Float16)w.z;
            Tt[c0 + i * 4 + 3][r] = (_Float16)w.w;
        }
    }
    __syncthreads();
    {
        const int n = t >> 2, ko = (t & 3) * 16;
        const size_t dst = (size_t)(blockIdx.y * 64 + n) * D_ + k0 + ko;
        *(int4*)&Wt[dst]     = *(int4*)&Tt[n][ko];
        *(int4*)&Wt[dst + 8] = *(int4*)&Tt[n][ko + 8];
    }
}

// ---------------------------------------------------------------------------
// Stage 1: QKV projection, f16 MFMA.  M-tile 64, N=192 (q|k|v), K-chunk 64.
// 256 threads = 4 waves; wave w owns output rows 16w..16w+15.
// ---------------------------------------------------------------------------
__global__ __launch_bounds__(256) void qkv_kernel(
    const float* __restrict__ x, const _Float16* __restrict__ Wt,
    _Float16* __restrict__ qf, _Float16* __restrict__ kf,
    _Float16* __restrict__ vT)
{
    __shared__ _Float16 Xs[64][72];    // [m][k]
    __shared__ _Float16 Ws[192][72];   // [n][k]

    const int t    = threadIdx.x;
    const int m0   = blockIdx.x * 64;
    const int lane = t & 63, wave = t >> 6;
    const int lid  = lane & 15, quad = lane >> 4;

    f32x4 acc[12];
#pragma unroll
    for (int i = 0; i < 12; ++i) acc[i] = f32x4{0.f, 0.f, 0.f, 0.f};

    const int xr = t >> 2, xo = (t & 3) * 16;

    for (int kc = 0; kc < D_; kc += 64) {
        __syncthreads();
        // stage X (fp32 -> f16)
        {
            _Float16 tmp[16];
#pragma unroll
            for (int i = 0; i < 4; ++i) {
                float4 xv = *(const float4*)&x[(size_t)(m0 + xr) * D_ + kc + xo + i * 4];
                tmp[i * 4 + 0] = (_Float16)xv.x;
                tmp[i * 4 + 1] = (_Float16)xv.y;
                tmp[i * 4 + 2] = (_Float16)xv.z;
                tmp[i * 4 + 3] = (_Float16)xv.w;
            }
            *(int4*)&Xs[xr][xo]     = *(int4*)&tmp[0];
            *(int4*)&Xs[xr][xo + 8] = *(int4*)&tmp[8];
        }
        // stage Wt chunk: 192 rows x 64 k = 1536 16B units
#pragma unroll
        for (int p = 0; p < 6; ++p) {
            const int idx = p * 256 + t;
            const int row = idx >> 3, u = idx & 7;
            *(int4*)&Ws[row][u * 8] = *(const int4*)&Wt[(size_t)row * D_ + kc + u * 8];
        }
        __syncthreads();

        const f16x8 a0 = *(const f16x8*)&Xs[wave * 16 + lid][quad * 8];
        const f16x8 a1 = *(const f16x8*)&Xs[wave * 16 + lid][32 + quad * 8];
#pragma unroll
        for (int nt = 0; nt < 12; ++nt) {
            f16x8 b0 = *(const f16x8*)&Ws[nt * 16 + lid][quad * 8];
            f16x8 b1 = *(const f16x8*)&Ws[nt * 16 + lid][32 + quad * 8];
            acc[nt] = __builtin_amdgcn_mfma_f32_16x16x32_f16(a0, b0, acc[nt], 0, 0, 0);
            acc[nt] = __builtin_amdgcn_mfma_f32_16x16x32_f16(a1, b1, acc[nt], 0, 0, 0);
        }
    }

    // epilogue: C/D layout col=lane&15, row=quad*4+reg
#pragma unroll
    for (int nt = 0; nt < 12; ++nt) {
        const int col = nt * 16 + lid;
#pragma unroll
        for (int r = 0; r < 4; ++r) {
            const int m = m0 + wave * 16 + quad * 4 + r;
            const _Float16 v = (_Float16)acc[nt][r];
            if (nt < 4)      qf[(size_t)m * HS_ + col] = v;
            else if (nt < 8) kf[(size_t)m * HS_ + (col - 64)] = v;
            else {
                const int bi = m >> 11, tl = m & 2047;
                vT[((size_t)(bi * 64 + (col - 128))) * T_ + tl] = v;
            }
        }
    }
}

// ---------------------------------------------------------------------------
// Stage 2: causal flash attention, f16 MFMA.  Q-tile 64, K-tile 64.
// 4 waves, wave w owns q-rows 16w..16w+15; softmax fully in-wave via shfl_xor.
// ---------------------------------------------------------------------------
__global__ __launch_bounds__(256) void attn_kernel(
    const _Float16* __restrict__ qf, const _Float16* __restrict__ kf,
    const _Float16* __restrict__ vT, float* __restrict__ out)
{
    __shared__ _Float16 Qs[64][72];   // [qrow][h]
    __shared__ _Float16 Ks[64][72];   // [krow][h]
    __shared__ _Float16 Vts[64][72];  // [h][krow]
    __shared__ _Float16 Ps[64][72];   // [qrow][krow]  (wave-private rows)

    const int t  = threadIdx.x;
    const int qi = blockIdx.x, b = blockIdx.y;
    const int q0 = qi * 64;
    const size_t bT = (size_t)b * T_;

    const int lane = t & 63, wave = t >> 6;
    const int lid  = lane & 15, quad = lane >> 4;
    const int sr = t >> 2, so = (t & 3) * 16;

    // stage Q tile
    {
        const size_t src = (bT + q0 + sr) * HS_ + so;
        *(int4*)&Qs[sr][so]     = *(const int4*)&qf[src];
        *(int4*)&Qs[sr][so + 8] = *(const int4*)&qf[src + 8];
    }
    __syncthreads();
    const f16x8 aq0 = *(const f16x8*)&Qs[wave * 16 + lid][quad * 8];
    const f16x8 aq1 = *(const f16x8*)&Qs[wave * 16 + lid][32 + quad * 8];

    f32x4 o[4];
#pragma unroll
    for (int i = 0; i < 4; ++i) o[i] = f32x4{0.f, 0.f, 0.f, 0.f};
    float mp[4] = {-1e30f, -1e30f, -1e30f, -1e30f};
    float lr[4] = {0.f, 0.f, 0.f, 0.f};

    const float SC = 0.125f * 1.44269504088896f;   // HS^-0.5 * log2(e)

    for (int kt = 0; kt <= qi; ++kt) {
        const int k0 = kt * 64;
        __syncthreads();   // previous iteration done reading Ks/Vts
        {
            const size_t ksrc = (bT + k0 + sr) * HS_ + so;
            *(int4*)&Ks[sr][so]     = *(const int4*)&kf[ksrc];
            *(int4*)&Ks[sr][so + 8] = *(const int4*)&kf[ksrc + 8];
            const size_t vsrc = ((size_t)(b * 64 + sr)) * T_ + k0 + so;
            *(int4*)&Vts[sr][so]     = *(const int4*)&vT[vsrc];
            *(int4*)&Vts[sr][so + 8] = *(const int4*)&vT[vsrc + 8];
        }
        __syncthreads();

        // S = Q.K^T  (wave strip 16 x 64)
        f32x4 s[4];
#pragma unroll
        for (int i = 0; i < 4; ++i) s[i] = f32x4{0.f, 0.f, 0.f, 0.f};
#pragma unroll
        for (int nt = 0; nt < 4; ++nt) {
            f16x8 b0 = *(const f16x8*)&Ks[nt * 16 + lid][quad * 8];
            f16x8 b1 = *(const f16x8*)&Ks[nt * 16 + lid][32 + quad * 8];
            s[nt] = __builtin_amdgcn_mfma_f32_16x16x32_f16(aq0, b0, s[nt], 0, 0, 0);
            s[nt] = __builtin_amdgcn_mfma_f32_16x16x32_f16(aq1, b1, s[nt], 0, 0, 0);
        }

        // scale (pre-multiplied by log2e) + causal mask on diagonal tile
        float sv[4][4];
        const bool diag = (kt == qi);
#pragma unroll
        for (int nt = 0; nt < 4; ++nt)
#pragma unroll
            for (int r = 0; r < 4; ++r) {
                float v = s[nt][r] * SC;
                if (diag && (nt * 16 + lid > wave * 16 + quad * 4 + r)) v = -1e30f;
                sv[nt][r] = v;
            }

        // in-wave online softmax (row = quad*4+r lives on 16 lanes of the quad)
        float pm[4], al[4], rs[4];
#pragma unroll
        for (int r = 0; r < 4; ++r)
            pm[r] = fmaxf(fmaxf(sv[0][r], sv[1][r]), fmaxf(sv[2][r], sv[3][r]));
#pragma unroll
        for (int d = 1; d < 16; d <<= 1)
#pragma unroll
            for (int r = 0; r < 4; ++r)
                pm[r] = fmaxf(pm[r], __shfl_xor(pm[r], d, 64));
#pragma unroll
        for (int r = 0; r < 4; ++r) {
            const float mn = fmaxf(mp[r], pm[r]);
            al[r] = exp2f(mp[r] - mn);
            mp[r] = mn;
            rs[r] = 0.f;
        }
#pragma unroll
        for (int nt = 0; nt < 4; ++nt)
#pragma unroll
            for (int r = 0; r < 4; ++r) {
                const float pv = exp2f(sv[nt][r] - mp[r]);
                sv[nt][r] = pv;
                rs[r] += pv;
            }
#pragma unroll
        for (int d = 1; d < 16; d <<= 1)
#pragma unroll
            for (int r = 0; r < 4; ++r)
                rs[r] += __shfl_xor(rs[r], d, 64);
#pragma unroll
        for (int r = 0; r < 4; ++r)
            lr[r] = lr[r] * al[r] + rs[r];
#pragma unroll
        for (int nt = 0; nt < 4; ++nt)
#pragma unroll
            for (int r = 0; r < 4; ++r)
                o[nt][r] *= al[r];

        // P -> LDS (wave-private rows, no barrier needed)
#pragma unroll
        for (int nt = 0; nt < 4; ++nt)
#pragma unroll
            for (int r = 0; r < 4; ++r)
                Ps[wave * 16 + quad * 4 + r][nt * 16 + lid] = (_Float16)sv[nt][r];

        // O += P.V   (A = P rows, B = V^T rows)
        const f16x8 ap0 = *(const f16x8*)&Ps[wave * 16 + lid][quad * 8];
        const f16x8 ap1 = *(const f16x8*)&Ps[wave * 16 + lid][32 + quad * 8];
#pragma unroll
        for (int nt = 0; nt < 4; ++nt) {
            f16x8 b0 = *(const f16x8*)&Vts[nt * 16 + lid][quad * 8];
            f16x8 b1 = *(const f16x8*)&Vts[nt * 16 + lid][32 + quad * 8];
            o[nt] = __builtin_amdgcn_mfma_f32_16x16x32_f16(ap0, b0, o[nt], 0, 0, 0);
            o[nt] = __builtin_amdgcn_mfma_f32_16x16x32_f16(ap1, b1, o[nt], 0, 0, 0);
        }
    }

    // epilogue
    float inv[4];
#pragma unroll
    for (int r = 0; r < 4; ++r) inv[r] = 1.0f / lr[r];
#pragma unroll
    for (int nt = 0; nt < 4; ++nt)
#pragma unroll
        for (int r = 0; r < 4; ++r)
            out[(bT + q0 + wave * 16 + quad * 4 + r) * HS_ + nt * 16 + lid] =
                o[nt][r] * inv[r];
}

// ---------------------------------------------------------------------------
extern "C" void kernel_launch(void* const* d_in, const int* in_sizes, int n_in,
                              void* d_out, int out_size, void* d_ws, size_t ws_size,
                              hipStream_t stream)
{
    const float* x  = (const float*)d_in[0];
    const float* Wq = (const float*)d_in[1];
    const float* Wk = (const float*)d_in[2];
    const float* Wv = (const float*)d_in[3];
    float* out = (float*)d_out;

    _Float16* w  = (_Float16*)d_ws;
    _Float16* qf = w;
    _Float16* kf = w + 1048576;
    _Float16* vT = w + 2097152;
    _Float16* Wt = w + 3145728;

    wt_kernel<<<dim3(16, 3), 256, 0, stream>>>(Wq, Wk, Wv, Wt);
    qkv_kernel<<<256, 256, 0, stream>>>(x, Wt, qf, kf, vT);
    attn_kernel<<<dim3(32, 8), 256, 0, stream>>>(qf, kf, vT, out);
}

// Round 3
// 191.079 us; speedup vs baseline: 2.5600x; 1.0140x over previous
//
#include <hip/hip_runtime.h>
#include <math.h>

#define B_ 8
#define T_ 2048
#define D_ 1024
#define HS_ 64

typedef _Float16 f16x8 __attribute__((ext_vector_type(8)));
typedef float f32x4 __attribute__((ext_vector_type(4)));

// ---------------------------------------------------------------------------
// ws layout (f16 elements unless noted):
//   qf : [B*T][64]      @ 0          (1,048,576)
//   kf : [B*T][64]      @ 1,048,576
//   vT : [B][64][T]     @ 2,097,152
//   Wt : [192][1024]    @ 3,145,728  (196,608)  rows: Wq^T|Wk^T|Wv^T
//   Op : [640][64][64]  @ 3,342,336  (2,621,440) unnormalized O partials
//   ml : [640][128] f32 @ byte 11,927,552 (m[64] then l[64] per slot)
// total 12,255,232 B  (ws known >= 12,582,912 B)
// ---------------------------------------------------------------------------

// Stage 0: transpose Wq|Wk|Wv (fp32 [1024][64]) -> Wt f16 [192][1024]
__global__ __launch_bounds__(256) void wt_kernel(
    const float* __restrict__ Wq, const float* __restrict__ Wk,
    const float* __restrict__ Wv, _Float16* __restrict__ Wt)
{
    __shared__ _Float16 Tt[64][72];
    const float* W = (blockIdx.y == 0) ? Wq : (blockIdx.y == 1) ? Wk : Wv;
    const int t  = threadIdx.x;
    const int k0 = blockIdx.x * 64;
    {
        const int r = t >> 2, c0 = (t & 3) * 16;
#pragma unroll
        for (int i = 0; i < 4; ++i) {
            float4 w = *(const float4*)&W[(size_t)(k0 + r) * HS_ + c0 + i * 4];
            Tt[c0 + i * 4 + 0][r] = (_Float16)w.x;
            Tt[c0 + i * 4 + 1][r] = (_Float16)w.y;
            Tt[c0 + i * 4 + 2][r] = (_Float16)w.z;
            Tt[c0 + i * 4 + 3][r] = (_Float16)w.w;
        }
    }
    __syncthreads();
    {
        const int n = t >> 2, ko = (t & 3) * 16;
        const size_t dst = (size_t)(blockIdx.y * 64 + n) * D_ + k0 + ko;
        *(int4*)&Wt[dst]     = *(int4*)&Tt[n][ko];
        *(int4*)&Wt[dst + 8] = *(int4*)&Tt[n][ko + 8];
    }
}

// ---------------------------------------------------------------------------
// Stage 1: QKV projection, f16 MFMA, no LDS / no barriers in the K-loop.
// Block = 4 waves; wave w owns rows m0+16w..+15, all 192 cols (12 N-tiles).
// A-frags straight from global x (fp32->f16 in regs); B-frags from L2-hot Wt.
// ---------------------------------------------------------------------------
__global__ __launch_bounds__(256) void qkv_kernel(
    const float* __restrict__ x, const _Float16* __restrict__ Wt,
    _Float16* __restrict__ qf, _Float16* __restrict__ kf,
    _Float16* __restrict__ vT)
{
    __shared__ _Float16 Cs[64][200];   // epilogue pack buffer (stride 400B, 16B-aligned)

    const int t    = threadIdx.x;
    const int m0   = blockIdx.x * 64;
    const int lane = t & 63, wave = t >> 6;
    const int lid  = lane & 15, quad = lane >> 4;

    const float*    xrow = x  + (size_t)(m0 + wave * 16 + lid) * D_ + quad * 8;
    const _Float16* wrow = Wt + (size_t)lid * D_ + quad * 8;

    f32x4 acc[12];
#pragma unroll
    for (int i = 0; i < 12; ++i) acc[i] = f32x4{0.f, 0.f, 0.f, 0.f};

#pragma unroll
    for (int kc = 0; kc < D_; kc += 64) {
        float4 x00 = *(const float4*)(xrow + kc);
        float4 x01 = *(const float4*)(xrow + kc + 4);
        float4 x10 = *(const float4*)(xrow + kc + 32);
        float4 x11 = *(const float4*)(xrow + kc + 36);
        f16x8 a0 = {(_Float16)x00.x, (_Float16)x00.y, (_Float16)x00.z, (_Float16)x00.w,
                    (_Float16)x01.x, (_Float16)x01.y, (_Float16)x01.z, (_Float16)x01.w};
        f16x8 a1 = {(_Float16)x10.x, (_Float16)x10.y, (_Float16)x10.z, (_Float16)x10.w,
                    (_Float16)x11.x, (_Float16)x11.y, (_Float16)x11.z, (_Float16)x11.w};
#pragma unroll
        for (int nt = 0; nt < 12; ++nt) {
            f16x8 b0 = *(const f16x8*)(wrow + (size_t)nt * 16 * D_ + kc);
            f16x8 b1 = *(const f16x8*)(wrow + (size_t)nt * 16 * D_ + kc + 32);
            acc[nt] = __builtin_amdgcn_mfma_f32_16x16x32_f16(a0, b0, acc[nt], 0, 0, 0);
            acc[nt] = __builtin_amdgcn_mfma_f32_16x16x32_f16(a1, b1, acc[nt], 0, 0, 0);
        }
    }

    // epilogue: C (f16) -> LDS, then coalesced global writes
#pragma unroll
    for (int nt = 0; nt < 12; ++nt)
#pragma unroll
        for (int r = 0; r < 4; ++r)
            Cs[wave * 16 + quad * 4 + r][nt * 16 + lid] = (_Float16)acc[nt][r];
    __syncthreads();

    const int row = t >> 2, c0 = (t & 3) * 16;
    const size_t orow = (size_t)(m0 + row) * HS_;
    *(int4*)&qf[orow + c0]     = *(int4*)&Cs[row][c0];
    *(int4*)&qf[orow + c0 + 8] = *(int4*)&Cs[row][c0 + 8];
    *(int4*)&kf[orow + c0]     = *(int4*)&Cs[row][64 + c0];
    *(int4*)&kf[orow + c0 + 8] = *(int4*)&Cs[row][64 + c0 + 8];
    // vT: transpose-gather the V block (h = row, t-offset = c0..c0+15)
    _Float16 tmp[16];
#pragma unroll
    for (int j = 0; j < 16; ++j) tmp[j] = Cs[c0 + j][128 + row];
    const int bi = m0 >> 11, m0loc = m0 & 2047;
    const size_t vrow = (size_t)(bi * 64 + row) * T_ + m0loc + c0;
    *(int4*)&vT[vrow]     = *(int4*)&tmp[0];
    *(int4*)&vT[vrow + 8] = *(int4*)&tmp[8];
}

// ---------------------------------------------------------------------------
// Stage 2: causal flash attention, split-K (chunks of 8 k-tiles = 512 keys).
// Block p of 80 per batch decodes to (qi, chunk).  4 waves over 64 q-rows.
// Single-chunk tiles (qi<8) write out directly; else unnormalized partials.
// ---------------------------------------------------------------------------
__global__ __launch_bounds__(256) void attn_kernel(
    const _Float16* __restrict__ qf, const _Float16* __restrict__ kf,
    const _Float16* __restrict__ vT, _Float16* __restrict__ Opart,
    float* __restrict__ ml, float* __restrict__ out)
{
    __shared__ _Float16 Qs[64][72];
    __shared__ _Float16 Ks[64][72];
    __shared__ _Float16 Vts[64][72];
    __shared__ _Float16 Ps[64][72];

    const int p = blockIdx.x, b = blockIdx.y;
    int qi, c;
    if (p < 8)       { qi = p;                  c = 0; }
    else if (p < 24) { qi = 8  + ((p - 8) >> 1);  c = (p - 8) & 1; }
    else if (p < 48) { qi = 16 + (p - 24) / 3;    c = (p - 24) % 3; }
    else             { qi = 24 + ((p - 48) >> 2); c = (p - 48) & 3; }
    const int kts = c * 8;
    const int kte = min(qi + 1, kts + 8);

    const int q0 = qi * 64;
    const size_t bT = (size_t)b * T_;
    const int t = threadIdx.x;
    const int lane = t & 63, wave = t >> 6;
    const int lid  = lane & 15, quad = lane >> 4;
    const int sr = t >> 2, so = (t & 3) * 16;

    // stage Q tile once
    {
        const size_t src = (bT + q0 + sr) * HS_ + so;
        *(int4*)&Qs[sr][so]     = *(const int4*)&qf[src];
        *(int4*)&Qs[sr][so + 8] = *(const int4*)&qf[src + 8];
    }
    __syncthreads();
    const f16x8 aq0 = *(const f16x8*)&Qs[wave * 16 + lid][quad * 8];
    const f16x8 aq1 = *(const f16x8*)&Qs[wave * 16 + lid][32 + quad * 8];

    f32x4 o[4];
#pragma unroll
    for (int i = 0; i < 4; ++i) o[i] = f32x4{0.f, 0.f, 0.f, 0.f};
    float mp[4] = {-1e30f, -1e30f, -1e30f, -1e30f};
    float lr[4] = {0.f, 0.f, 0.f, 0.f};

    const float SC = 0.125f * 1.44269504088896f;   // HS^-0.5 * log2(e)

    // register prefetch of K/V tiles
    int4 kr0, kr1, vr0, vr1;
    {
        const int k0 = kts * 64;
        const size_t ksrc = (bT + k0 + sr) * HS_ + so;
        kr0 = *(const int4*)&kf[ksrc]; kr1 = *(const int4*)&kf[ksrc + 8];
        const size_t vsrc = (size_t)(b * 64 + sr) * T_ + k0 + so;
        vr0 = *(const int4*)&vT[vsrc]; vr1 = *(const int4*)&vT[vsrc + 8];
    }

    for (int kt = kts; kt < kte; ++kt) {
        __syncthreads();   // previous iteration done reading Ks/Vts
        *(int4*)&Ks[sr][so]      = kr0;
        *(int4*)&Ks[sr][so + 8]  = kr1;
        *(int4*)&Vts[sr][so]     = vr0;
        *(int4*)&Vts[sr][so + 8] = vr1;
        __syncthreads();
        if (kt + 1 < kte) {   // issue next tile's loads; latency hidden by compute
            const int k0n = (kt + 1) * 64;
            const size_t ksrc = (bT + k0n + sr) * HS_ + so;
            kr0 = *(const int4*)&kf[ksrc]; kr1 = *(const int4*)&kf[ksrc + 8];
            const size_t vsrc = (size_t)(b * 64 + sr) * T_ + k0n + so;
            vr0 = *(const int4*)&vT[vsrc]; vr1 = *(const int4*)&vT[vsrc + 8];
        }

        // S = Q.K^T  (wave strip 16 x 64)
        f32x4 s[4];
#pragma unroll
        for (int i = 0; i < 4; ++i) s[i] = f32x4{0.f, 0.f, 0.f, 0.f};
#pragma unroll
        for (int nt = 0; nt < 4; ++nt) {
            f16x8 b0 = *(const f16x8*)&Ks[nt * 16 + lid][quad * 8];
            f16x8 b1 = *(const f16x8*)&Ks[nt * 16 + lid][32 + quad * 8];
            s[nt] = __builtin_amdgcn_mfma_f32_16x16x32_f16(aq0, b0, s[nt], 0, 0, 0);
            s[nt] = __builtin_amdgcn_mfma_f32_16x16x32_f16(aq1, b1, s[nt], 0, 0, 0);
        }

        // scale (pre-multiplied by log2e) + causal mask on diagonal tile
        float sv[4][4];
        const bool diag = (kt == qi);
        const int k0 = kt * 64;
        (void)k0;
#pragma unroll
        for (int nt = 0; nt < 4; ++nt)
#pragma unroll
            for (int r = 0; r < 4; ++r) {
                float v = s[nt][r] * SC;
                if (diag && (nt * 16 + lid > wave * 16 + quad * 4 + r)) v = -1e30f;
                sv[nt][r] = v;
            }

        // in-wave online softmax
        float pm[4], al[4], rs[4];
#pragma unroll
        for (int r = 0; r < 4; ++r)
            pm[r] = fmaxf(fmaxf(sv[0][r], sv[1][r]), fmaxf(sv[2][r], sv[3][r]));
#pragma unroll
        for (int d = 1; d < 16; d <<= 1)
#pragma unroll
            for (int r = 0; r < 4; ++r)
                pm[r] = fmaxf(pm[r], __shfl_xor(pm[r], d, 64));
#pragma unroll
        for (int r = 0; r < 4; ++r) {
            const float mn = fmaxf(mp[r], pm[r]);
            al[r] = exp2f(mp[r] - mn);
            mp[r] = mn;
            rs[r] = 0.f;
        }
#pragma unroll
        for (int nt = 0; nt < 4; ++nt)
#pragma unroll
            for (int r = 0; r < 4; ++r) {
                const float pv = exp2f(sv[nt][r] - mp[r]);
                sv[nt][r] = pv;
                rs[r] += pv;
            }
#pragma unroll
        for (int d = 1; d < 16; d <<= 1)
#pragma unroll
            for (int r = 0; r < 4; ++r)
                rs[r] += __shfl_xor(rs[r], d, 64);
#pragma unroll
        for (int r = 0; r < 4; ++r)
            lr[r] = lr[r] * al[r] + rs[r];
#pragma unroll
        for (int nt = 0; nt < 4; ++nt)
#pragma unroll
            for (int r = 0; r < 4; ++r)
                o[nt][r] *= al[r];

        // P -> LDS (wave-private rows)
#pragma unroll
        for (int nt = 0; nt < 4; ++nt)
#pragma unroll
            for (int r = 0; r < 4; ++r)
                Ps[wave * 16 + quad * 4 + r][nt * 16 + lid] = (_Float16)sv[nt][r];

        // O += P.V
        const f16x8 ap0 = *(const f16x8*)&Ps[wave * 16 + lid][quad * 8];
        const f16x8 ap1 = *(const f16x8*)&Ps[wave * 16 + lid][32 + quad * 8];
#pragma unroll
        for (int nt = 0; nt < 4; ++nt) {
            f16x8 b0 = *(const f16x8*)&Vts[nt * 16 + lid][quad * 8];
            f16x8 b1 = *(const f16x8*)&Vts[nt * 16 + lid][32 + quad * 8];
            o[nt] = __builtin_amdgcn_mfma_f32_16x16x32_f16(ap0, b0, o[nt], 0, 0, 0);
            o[nt] = __builtin_amdgcn_mfma_f32_16x16x32_f16(ap1, b1, o[nt], 0, 0, 0);
        }
    }

    const int nc = (qi >> 3) + 1;
    if (nc == 1) {
        float inv[4];
#pragma unroll
        for (int r = 0; r < 4; ++r) inv[r] = 1.0f / lr[r];
#pragma unroll
        for (int nt = 0; nt < 4; ++nt)
#pragma unroll
            for (int r = 0; r < 4; ++r)
                out[(bT + q0 + wave * 16 + quad * 4 + r) * HS_ + nt * 16 + lid] =
                    o[nt][r] * inv[r];
    } else {
        const int slot = b * 80 + p;
        _Float16* Ob = Opart + (size_t)slot * 4096;
#pragma unroll
        for (int nt = 0; nt < 4; ++nt)
#pragma unroll
            for (int r = 0; r < 4; ++r)
                Ob[(wave * 16 + quad * 4 + r) * 64 + nt * 16 + lid] = (_Float16)o[nt][r];
        if (lid == 0) {
#pragma unroll
            for (int r = 0; r < 4; ++r) {
                const int row = wave * 16 + quad * 4 + r;
                ml[(size_t)slot * 128 + row]      = mp[r];
                ml[(size_t)slot * 128 + 64 + row] = lr[r];
            }
        }
    }
}

// ---------------------------------------------------------------------------
// Stage 3: combine partials for q-tiles with >=2 chunks (qi >= 8).
// ---------------------------------------------------------------------------
__global__ __launch_bounds__(256) void combine_kernel(
    const _Float16* __restrict__ Opart, const float* __restrict__ ml,
    float* __restrict__ out)
{
    const int qi = 8 + blockIdx.x, b = blockIdx.y;
    const int g = qi >> 3, nc = g + 1;
    const int poff = 8 * (g * (g + 1) / 2) + (qi & 7) * nc;
    const int t = threadIdx.x, row = t >> 2, c0 = (t & 3) * 16;

    float mv[4], M = -1e30f;
#pragma unroll
    for (int cc = 0; cc < 4; ++cc) {
        mv[cc] = (cc < nc) ? ml[(size_t)(b * 80 + poff + cc) * 128 + row] : -1e30f;
        M = fmaxf(M, mv[cc]);
    }
    float L = 0.f, accv[16];
#pragma unroll
    for (int j = 0; j < 16; ++j) accv[j] = 0.f;
#pragma unroll
    for (int cc = 0; cc < 4; ++cc) {
        if (cc < nc) {   // nc is block-uniform: no divergence
            const int slot = b * 80 + poff + cc;
            const float w = exp2f(mv[cc] - M);
            L += ml[(size_t)slot * 128 + 64 + row] * w;
            f16x8 o0 = *(const f16x8*)&Opart[(size_t)slot * 4096 + row * 64 + c0];
            f16x8 o1 = *(const f16x8*)&Opart[(size_t)slot * 4096 + row * 64 + c0 + 8];
#pragma unroll
            for (int j = 0; j < 8; ++j) {
                accv[j]     += w * (float)o0[j];
                accv[8 + j] += w * (float)o1[j];
            }
        }
    }
    const float inv = 1.0f / L;
    const size_t obase = ((size_t)b * T_ + qi * 64 + row) * HS_ + c0;
#pragma unroll
    for (int u = 0; u < 4; ++u) {
        float4 r4;
        r4.x = accv[u * 4 + 0] * inv;
        r4.y = accv[u * 4 + 1] * inv;
        r4.z = accv[u * 4 + 2] * inv;
        r4.w = accv[u * 4 + 3] * inv;
        *(float4*)&out[obase + u * 4] = r4;
    }
}

// ---------------------------------------------------------------------------
extern "C" void kernel_launch(void* const* d_in, const int* in_sizes, int n_in,
                              void* d_out, int out_size, void* d_ws, size_t ws_size,
                              hipStream_t stream)
{
    const float* x  = (const float*)d_in[0];
    const float* Wq = (const float*)d_in[1];
    const float* Wk = (const float*)d_in[2];
    const float* Wv = (const float*)d_in[3];
    float* out = (float*)d_out;

    _Float16* w   = (_Float16*)d_ws;
    _Float16* qf  = w;
    _Float16* kf  = w + 1048576;
    _Float16* vT  = w + 2097152;
    _Float16* Wt  = w + 3145728;
    _Float16* Op  = w + 3342336;             // 3,145,728 + 196,608
    float*    ml  = (float*)(w + 5963776);   // 3,342,336 + 2,621,440

    wt_kernel<<<dim3(16, 3), 256, 0, stream>>>(Wq, Wk, Wv, Wt);
    qkv_kernel<<<256, 256, 0, stream>>>(x, Wt, qf, kf, vT);
    attn_kernel<<<dim3(80, 8), 256, 0, stream>>>(qf, kf, vT, Op, ml, out);
    combine_kernel<<<dim3(24, 8), 256, 0, stream>>>(Op, ml, out);
}

// Round 4
// 172.070 us; speedup vs baseline: 2.8429x; 1.1105x over previous
//
#include <hip/hip_runtime.h>
#include <math.h>

#define B_ 8
#define T_ 2048
#define D_ 1024
#define HS_ 64

typedef _Float16 f16x8 __attribute__((ext_vector_type(8)));
typedef float f32x4 __attribute__((ext_vector_type(4)));

// ---------------------------------------------------------------------------
// ws layout (f16 elements unless noted):
//   qf : [B*T][64]      @ 0          (1,048,576)
//   kf : [B*T][64]      @ 1,048,576
//   vT : [B][64][T]     @ 2,097,152
//   Wt : [192][1024]    @ 3,145,728  (196,608)  rows: Wq^T|Wk^T|Wv^T
//   Op : [640][64][64]  @ 3,342,336  (2,621,440) unnormalized O partials
//   ml : [640][128] f32 @ byte 11,927,552 (m[64] then l[64] per slot)
// total 12,255,232 B  (proven to fit in Round 3)
// ---------------------------------------------------------------------------

// Stage 0: transpose Wq|Wk|Wv (fp32 [1024][64]) -> Wt f16 [192][1024]
__global__ __launch_bounds__(256) void wt_kernel(
    const float* __restrict__ Wq, const float* __restrict__ Wk,
    const float* __restrict__ Wv, _Float16* __restrict__ Wt)
{
    __shared__ _Float16 Tt[64][72];
    const float* W = (blockIdx.y == 0) ? Wq : (blockIdx.y == 1) ? Wk : Wv;
    const int t  = threadIdx.x;
    const int k0 = blockIdx.x * 64;
    {
        const int r = t >> 2, c0 = (t & 3) * 16;
#pragma unroll
        for (int i = 0; i < 4; ++i) {
            float4 w = *(const float4*)&W[(size_t)(k0 + r) * HS_ + c0 + i * 4];
            Tt[c0 + i * 4 + 0][r] = (_Float16)w.x;
            Tt[c0 + i * 4 + 1][r] = (_Float16)w.y;
            Tt[c0 + i * 4 + 2][r] = (_Float16)w.z;
            Tt[c0 + i * 4 + 3][r] = (_Float16)w.w;
        }
    }
    __syncthreads();
    {
        const int n = t >> 2, ko = (t & 3) * 16;
        const size_t dst = (size_t)(blockIdx.y * 64 + n) * D_ + k0 + ko;
        *(int4*)&Wt[dst]     = *(int4*)&Tt[n][ko];
        *(int4*)&Wt[dst + 8] = *(int4*)&Tt[n][ko + 8];
    }
}

// ---------------------------------------------------------------------------
// Stage 1: QKV projection, f16 MFMA.  512 threads = 8 waves.
// Waves 0-3: K[0,512); waves 4-7: K[512,1024).  Wave w4 owns rows 16*w4..+15,
// all 12 N-tiles.  K-loop: register-prefetch pipeline (depth 1, steps of 32),
// NO LDS / NO barriers in the loop -> loads stay in flight across MFMAs.
// Epilogue: f32 cross-K-half reduce through LDS, then coalesced f16 writes.
// ---------------------------------------------------------------------------
__global__ __launch_bounds__(512, 2) void qkv_kernel(
    const float* __restrict__ x, const _Float16* __restrict__ Wt,
    _Float16* __restrict__ qf, _Float16* __restrict__ kf,
    _Float16* __restrict__ vT)
{
    __shared__ float    CsF[64][196];   // f32 partial dump (kw=1 waves)
    __shared__ _Float16 CsH[64][200];   // packed f16 result

    const int t    = threadIdx.x;
    const int m0   = blockIdx.x * 64;
    const int lane = t & 63, wave = t >> 6;
    const int kw   = wave >> 2;          // K-half
    const int w4   = wave & 3;           // row group
    const int lid  = lane & 15, quad = lane >> 4;

    const float*    xp = x  + (size_t)(m0 + w4 * 16 + lid) * D_ + kw * 512 + quad * 8;
    const _Float16* wp = Wt + (size_t)lid * D_ + kw * 512 + quad * 8;

    f32x4 acc[12];
#pragma unroll
    for (int i = 0; i < 12; ++i) acc[i] = f32x4{0.f, 0.f, 0.f, 0.f};

    // prologue: load step 0
    float4 xc0 = *(const float4*)(xp);
    float4 xc1 = *(const float4*)(xp + 4);
    f16x8 bc[12];
#pragma unroll
    for (int nt = 0; nt < 12; ++nt)
        bc[nt] = *(const f16x8*)(wp + (size_t)nt * 16 * D_);

    // 16 steps of k=32 over this wave's 512-deep K half
#pragma unroll
    for (int s = 0; s < 16; ++s) {
        float4 xn0, xn1;
        f16x8 bn[12];
        if (s < 15) {   // issue next step's loads before consuming current
            const int ko = (s + 1) * 32;
            xn0 = *(const float4*)(xp + ko);
            xn1 = *(const float4*)(xp + ko + 4);
#pragma unroll
            for (int nt = 0; nt < 12; ++nt)
                bn[nt] = *(const f16x8*)(wp + (size_t)nt * 16 * D_ + ko);
        }
        const f16x8 a = {(_Float16)xc0.x, (_Float16)xc0.y, (_Float16)xc0.z, (_Float16)xc0.w,
                         (_Float16)xc1.x, (_Float16)xc1.y, (_Float16)xc1.z, (_Float16)xc1.w};
#pragma unroll
        for (int nt = 0; nt < 12; ++nt)
            acc[nt] = __builtin_amdgcn_mfma_f32_16x16x32_f16(a, bc[nt], acc[nt], 0, 0, 0);
        if (s < 15) {
            xc0 = xn0; xc1 = xn1;
#pragma unroll
            for (int nt = 0; nt < 12; ++nt) bc[nt] = bn[nt];
        }
    }

    // ---- epilogue: reduce the two K-halves, pack f16, coalesced writes ----
    if (kw == 1) {
#pragma unroll
        for (int nt = 0; nt < 12; ++nt)
#pragma unroll
            for (int r = 0; r < 4; ++r)
                CsF[w4 * 16 + quad * 4 + r][nt * 16 + lid] = acc[nt][r];
    }
    __syncthreads();
    if (kw == 0) {
#pragma unroll
        for (int nt = 0; nt < 12; ++nt)
#pragma unroll
            for (int r = 0; r < 4; ++r) {
                const float v = acc[nt][r] + CsF[w4 * 16 + quad * 4 + r][nt * 16 + lid];
                CsH[w4 * 16 + quad * 4 + r][nt * 16 + lid] = (_Float16)v;
            }
    }
    __syncthreads();

    const int row = t >> 3;          // 0..63
    const int c8  = (t & 7) * 8;     // 0..56 step 8 (f16 units, 16 B)
    const size_t orow = (size_t)(m0 + row) * HS_;
    *(int4*)&qf[orow + c8] = *(int4*)&CsH[row][c8];
    *(int4*)&kf[orow + c8] = *(int4*)&CsH[row][64 + c8];
    // vT: transpose-gather V block (h = row, t-offset = c8..c8+7)
    _Float16 tmp[8];
#pragma unroll
    for (int j = 0; j < 8; ++j) tmp[j] = CsH[c8 + j][128 + row];
    const int bi = m0 >> 11, m0loc = m0 & 2047;
    *(int4*)&vT[(size_t)(bi * 64 + row) * T_ + m0loc + c8] = *(int4*)&tmp[0];
}

// ---------------------------------------------------------------------------
// Stage 2: causal flash attention, split-K (chunks of 8 k-tiles = 512 keys).
// (unchanged from Round 3)
// ---------------------------------------------------------------------------
__global__ __launch_bounds__(256) void attn_kernel(
    const _Float16* __restrict__ qf, const _Float16* __restrict__ kf,
    const _Float16* __restrict__ vT, _Float16* __restrict__ Opart,
    float* __restrict__ ml, float* __restrict__ out)
{
    __shared__ _Float16 Qs[64][72];
    __shared__ _Float16 Ks[64][72];
    __shared__ _Float16 Vts[64][72];
    __shared__ _Float16 Ps[64][72];

    const int p = blockIdx.x, b = blockIdx.y;
    int qi, c;
    if (p < 8)       { qi = p;                  c = 0; }
    else if (p < 24) { qi = 8  + ((p - 8) >> 1);  c = (p - 8) & 1; }
    else if (p < 48) { qi = 16 + (p - 24) / 3;    c = (p - 24) % 3; }
    else             { qi = 24 + ((p - 48) >> 2); c = (p - 48) & 3; }
    const int kts = c * 8;
    const int kte = min(qi + 1, kts + 8);

    const int q0 = qi * 64;
    const size_t bT = (size_t)b * T_;
    const int t = threadIdx.x;
    const int lane = t & 63, wave = t >> 6;
    const int lid  = lane & 15, quad = lane >> 4;
    const int sr = t >> 2, so = (t & 3) * 16;

    {
        const size_t src = (bT + q0 + sr) * HS_ + so;
        *(int4*)&Qs[sr][so]     = *(const int4*)&qf[src];
        *(int4*)&Qs[sr][so + 8] = *(const int4*)&qf[src + 8];
    }
    __syncthreads();
    const f16x8 aq0 = *(const f16x8*)&Qs[wave * 16 + lid][quad * 8];
    const f16x8 aq1 = *(const f16x8*)&Qs[wave * 16 + lid][32 + quad * 8];

    f32x4 o[4];
#pragma unroll
    for (int i = 0; i < 4; ++i) o[i] = f32x4{0.f, 0.f, 0.f, 0.f};
    float mp[4] = {-1e30f, -1e30f, -1e30f, -1e30f};
    float lr[4] = {0.f, 0.f, 0.f, 0.f};

    const float SC = 0.125f * 1.44269504088896f;   // HS^-0.5 * log2(e)

    int4 kr0, kr1, vr0, vr1;
    {
        const int k0 = kts * 64;
        const size_t ksrc = (bT + k0 + sr) * HS_ + so;
        kr0 = *(const int4*)&kf[ksrc]; kr1 = *(const int4*)&kf[ksrc + 8];
        const size_t vsrc = (size_t)(b * 64 + sr) * T_ + k0 + so;
        vr0 = *(const int4*)&vT[vsrc]; vr1 = *(const int4*)&vT[vsrc + 8];
    }

    for (int kt = kts; kt < kte; ++kt) {
        __syncthreads();
        *(int4*)&Ks[sr][so]      = kr0;
        *(int4*)&Ks[sr][so + 8]  = kr1;
        *(int4*)&Vts[sr][so]     = vr0;
        *(int4*)&Vts[sr][so + 8] = vr1;
        __syncthreads();
        if (kt + 1 < kte) {
            const int k0n = (kt + 1) * 64;
            const size_t ksrc = (bT + k0n + sr) * HS_ + so;
            kr0 = *(const int4*)&kf[ksrc]; kr1 = *(const int4*)&kf[ksrc + 8];
            const size_t vsrc = (size_t)(b * 64 + sr) * T_ + k0n + so;
            vr0 = *(const int4*)&vT[vsrc]; vr1 = *(const int4*)&vT[vsrc + 8];
        }

        f32x4 s[4];
#pragma unroll
        for (int i = 0; i < 4; ++i) s[i] = f32x4{0.f, 0.f, 0.f, 0.f};
#pragma unroll
        for (int nt = 0; nt < 4; ++nt) {
            f16x8 b0 = *(const f16x8*)&Ks[nt * 16 + lid][quad * 8];
            f16x8 b1 = *(const f16x8*)&Ks[nt * 16 + lid][32 + quad * 8];
            s[nt] = __builtin_amdgcn_mfma_f32_16x16x32_f16(aq0, b0, s[nt], 0, 0, 0);
            s[nt] = __builtin_amdgcn_mfma_f32_16x16x32_f16(aq1, b1, s[nt], 0, 0, 0);
        }

        float sv[4][4];
        const bool diag = (kt == qi);
#pragma unroll
        for (int nt = 0; nt < 4; ++nt)
#pragma unroll
            for (int r = 0; r < 4; ++r) {
                float v = s[nt][r] * SC;
                if (diag && (nt * 16 + lid > wave * 16 + quad * 4 + r)) v = -1e30f;
                sv[nt][r] = v;
            }

        float pm[4], al[4], rs[4];
#pragma unroll
        for (int r = 0; r < 4; ++r)
            pm[r] = fmaxf(fmaxf(sv[0][r], sv[1][r]), fmaxf(sv[2][r], sv[3][r]));
#pragma unroll
        for (int d = 1; d < 16; d <<= 1)
#pragma unroll
            for (int r = 0; r < 4; ++r)
                pm[r] = fmaxf(pm[r], __shfl_xor(pm[r], d, 64));
#pragma unroll
        for (int r = 0; r < 4; ++r) {
            const float mn = fmaxf(mp[r], pm[r]);
            al[r] = exp2f(mp[r] - mn);
            mp[r] = mn;
            rs[r] = 0.f;
        }
#pragma unroll
        for (int nt = 0; nt < 4; ++nt)
#pragma unroll
            for (int r = 0; r < 4; ++r) {
                const float pv = exp2f(sv[nt][r] - mp[r]);
                sv[nt][r] = pv;
                rs[r] += pv;
            }
#pragma unroll
        for (int d = 1; d < 16; d <<= 1)
#pragma unroll
            for (int r = 0; r < 4; ++r)
                rs[r] += __shfl_xor(rs[r], d, 64);
#pragma unroll
        for (int r = 0; r < 4; ++r)
            lr[r] = lr[r] * al[r] + rs[r];
#pragma unroll
        for (int nt = 0; nt < 4; ++nt)
#pragma unroll
            for (int r = 0; r < 4; ++r)
                o[nt][r] *= al[r];

#pragma unroll
        for (int nt = 0; nt < 4; ++nt)
#pragma unroll
            for (int r = 0; r < 4; ++r)
                Ps[wave * 16 + quad * 4 + r][nt * 16 + lid] = (_Float16)sv[nt][r];

        const f16x8 ap0 = *(const f16x8*)&Ps[wave * 16 + lid][quad * 8];
        const f16x8 ap1 = *(const f16x8*)&Ps[wave * 16 + lid][32 + quad * 8];
#pragma unroll
        for (int nt = 0; nt < 4; ++nt) {
            f16x8 b0 = *(const f16x8*)&Vts[nt * 16 + lid][quad * 8];
            f16x8 b1 = *(const f16x8*)&Vts[nt * 16 + lid][32 + quad * 8];
            o[nt] = __builtin_amdgcn_mfma_f32_16x16x32_f16(ap0, b0, o[nt], 0, 0, 0);
            o[nt] = __builtin_amdgcn_mfma_f32_16x16x32_f16(ap1, b1, o[nt], 0, 0, 0);
        }
    }

    const int nc = (qi >> 3) + 1;
    if (nc == 1) {
        float inv[4];
#pragma unroll
        for (int r = 0; r < 4; ++r) inv[r] = 1.0f / lr[r];
#pragma unroll
        for (int nt = 0; nt < 4; ++nt)
#pragma unroll
            for (int r = 0; r < 4; ++r)
                out[(bT + q0 + wave * 16 + quad * 4 + r) * HS_ + nt * 16 + lid] =
                    o[nt][r] * inv[r];
    } else {
        const int slot = b * 80 + p;
        _Float16* Ob = Opart + (size_t)slot * 4096;
#pragma unroll
        for (int nt = 0; nt < 4; ++nt)
#pragma unroll
            for (int r = 0; r < 4; ++r)
                Ob[(wave * 16 + quad * 4 + r) * 64 + nt * 16 + lid] = (_Float16)o[nt][r];
        if (lid == 0) {
#pragma unroll
            for (int r = 0; r < 4; ++r) {
                const int row = wave * 16 + quad * 4 + r;
                ml[(size_t)slot * 128 + row]      = mp[r];
                ml[(size_t)slot * 128 + 64 + row] = lr[r];
            }
        }
    }
}

// ---------------------------------------------------------------------------
// Stage 3: combine partials for q-tiles with >=2 chunks (qi >= 8).
// (unchanged from Round 3)
// ---------------------------------------------------------------------------
__global__ __launch_bounds__(256) void combine_kernel(
    const _Float16* __restrict__ Opart, const float* __restrict__ ml,
    float* __restrict__ out)
{
    const int qi = 8 + blockIdx.x, b = blockIdx.y;
    const int g = qi >> 3, nc = g + 1;
    const int poff = 8 * (g * (g + 1) / 2) + (qi & 7) * nc;
    const int t = threadIdx.x, row = t >> 2, c0 = (t & 3) * 16;

    float mv[4], M = -1e30f;
#pragma unroll
    for (int cc = 0; cc < 4; ++cc) {
        mv[cc] = (cc < nc) ? ml[(size_t)(b * 80 + poff + cc) * 128 + row] : -1e30f;
        M = fmaxf(M, mv[cc]);
    }
    float L = 0.f, accv[16];
#pragma unroll
    for (int j = 0; j < 16; ++j) accv[j] = 0.f;
#pragma unroll
    for (int cc = 0; cc < 4; ++cc) {
        if (cc < nc) {
            const int slot = b * 80 + poff + cc;
            const float w = exp2f(mv[cc] - M);
            L += ml[(size_t)slot * 128 + 64 + row] * w;
            f16x8 o0 = *(const f16x8*)&Opart[(size_t)slot * 4096 + row * 64 + c0];
            f16x8 o1 = *(const f16x8*)&Opart[(size_t)slot * 4096 + row * 64 + c0 + 8];
#pragma unroll
            for (int j = 0; j < 8; ++j) {
                accv[j]     += w * (float)o0[j];
                accv[8 + j] += w * (float)o1[j];
            }
        }
    }
    const float inv = 1.0f / L;
    const size_t obase = ((size_t)b * T_ + qi * 64 + row) * HS_ + c0;
#pragma unroll
    for (int u = 0; u < 4; ++u) {
        float4 r4;
        r4.x = accv[u * 4 + 0] * inv;
        r4.y = accv[u * 4 + 1] * inv;
        r4.z = accv[u * 4 + 2] * inv;
        r4.w = accv[u * 4 + 3] * inv;
        *(float4*)&out[obase + u * 4] = r4;
    }
}

// ---------------------------------------------------------------------------
extern "C" void kernel_launch(void* const* d_in, const int* in_sizes, int n_in,
                              void* d_out, int out_size, void* d_ws, size_t ws_size,
                              hipStream_t stream)
{
    const float* x  = (const float*)d_in[0];
    const float* Wq = (const float*)d_in[1];
    const float* Wk = (const float*)d_in[2];
    const float* Wv = (const float*)d_in[3];
    float* out = (float*)d_out;

    _Float16* w   = (_Float16*)d_ws;
    _Float16* qf  = w;
    _Float16* kf  = w + 1048576;
    _Float16* vT  = w + 2097152;
    _Float16* Wt  = w + 3145728;
    _Float16* Op  = w + 3342336;             // 3,145,728 + 196,608
    float*    ml  = (float*)(w + 5963776);   // 3,342,336 + 2,621,440

    wt_kernel<<<dim3(16, 3), 256, 0, stream>>>(Wq, Wk, Wv, Wt);
    qkv_kernel<<<256, 512, 0, stream>>>(x, Wt, qf, kf, vT);
    attn_kernel<<<dim3(80, 8), 256, 0, stream>>>(qf, kf, vT, Op, ml, out);
    combine_kernel<<<dim3(24, 8), 256, 0, stream>>>(Op, ml, out);
}